// Round 7
// baseline (786.977 us; speedup 1.0000x reference)
//
#include <hip/hip_runtime.h>
#include <hip/hip_bf16.h>

#define N_NODES 100000
#define N_EDGES 3200000
#define DFEAT 256
#define UNITS 256

#define CHUNK 512
#define CHUNK_SHIFT 9
#define NCHUNKS ((N_NODES + CHUNK - 1) / CHUNK)   // 196

#define BIN_TILE 2048
#define BIN_NWG ((N_EDGES + BIN_TILE - 1) / BIN_TILE)   // 1563
#define PADC 208                                  // padded chunk stride in hist_all

#define SLICES 16
#define FS 16                                      // features per slice (32 B bf16)
#define GAT_BLOCKS 2048                            // gather grid (256/XCD)

typedef short bf16x8 __attribute__((ext_vector_type(8)));
typedef float f32x4 __attribute__((ext_vector_type(4)));

// RNE float -> bf16 bits
__device__ __forceinline__ unsigned short f2bf(float f) {
    union { float f; unsigned u; } v; v.f = f;
    unsigned u = v.u;
    u += 0x7FFFu + ((u >> 16) & 1u);
    return (unsigned short)(u >> 16);
}

// ---------------------------------------------------------------------------
// Converts. Blocks [0,1563): x (fp32 row-major) -> xs (bf16 SLICE-MAJOR:
// xs[s][node][16f]), so the gather's per-XCD working set is one contiguous
// 3.2 MB slice. Block handles 64 nodes; thread (s=tid>>4, j=tid&15) writes
// nodes n0+4j..+3 of slice s = 128 B contiguous.
// Blocks [1563, 1563+256): W [k][n] fp32 -> Wt [n][k] bf16.
// ---------------------------------------------------------------------------
__global__ __launch_bounds__(256) void convert_xw(const float* __restrict__ x,
                                                  unsigned short* __restrict__ xs,
                                                  const float* __restrict__ w,
                                                  unsigned short* __restrict__ wt) {
    if (blockIdx.x < 1563) {
        const int n0 = blockIdx.x * 64;
        const int s = threadIdx.x >> 4;
        const int j = threadIdx.x & 15;
#pragma unroll
        for (int i = 0; i < 4; ++i) {
            const int n = n0 + j * 4 + i;
            if (n < N_NODES) {
                const float4* src = (const float4*)(x + (size_t)n * DFEAT + s * FS);
                float4 v0 = src[0], v1 = src[1], v2 = src[2], v3 = src[3];
                unsigned short* dst = xs + ((size_t)s * N_NODES + n) * FS;
                *(ushort4*)(dst)      = make_ushort4(f2bf(v0.x), f2bf(v0.y), f2bf(v0.z), f2bf(v0.w));
                *(ushort4*)(dst + 4)  = make_ushort4(f2bf(v1.x), f2bf(v1.y), f2bf(v1.z), f2bf(v1.w));
                *(ushort4*)(dst + 8)  = make_ushort4(f2bf(v2.x), f2bf(v2.y), f2bf(v2.z), f2bf(v2.w));
                *(ushort4*)(dst + 12) = make_ushort4(f2bf(v3.x), f2bf(v3.y), f2bf(v3.z), f2bf(v3.w));
            }
        }
    } else {
        int n = blockIdx.x - 1563, k = threadIdx.x;
        wt[n * DFEAT + k] = f2bf(w[k * UNITS + n]);
    }
}

// ---------------------------------------------------------------------------
// CSR build — round-3 measured-best structure, verbatim (538 us total path).
// ---------------------------------------------------------------------------
__global__ __launch_bounds__(256) void chunk_hist(const int* __restrict__ erow,
                                                  int* __restrict__ hist_all) {
    __shared__ int h[256];
    const int tid = threadIdx.x;
    h[tid] = 0;
    __syncthreads();
    const int base = blockIdx.x * BIN_TILE;
#pragma unroll
    for (int j = 0; j < 8; ++j) {
        int e = base + j * 256 + tid;
        if (e < N_EDGES) atomicAdd(&h[erow[e] >> CHUNK_SHIFT], 1);
    }
    __syncthreads();
    if (tid < NCHUNKS) hist_all[blockIdx.x * PADC + tid] = h[tid];
}

__global__ __launch_bounds__(256) void col_scan(int* __restrict__ hist_all,
                                                int* __restrict__ chunk_cnt) {
    __shared__ int t[256];
    const int b = blockIdx.x;
    const int tid = threadIdx.x;
    int v[7]; int local = 0;
#pragma unroll
    for (int j = 0; j < 7; ++j) {
        int w = tid * 7 + j;
        v[j] = (w < BIN_NWG) ? hist_all[w * PADC + b] : 0;
        local += v[j];
    }
    t[tid] = local;
    __syncthreads();
    for (int off = 1; off < 256; off <<= 1) {
        int u = 0;
        if (tid >= off) u = t[tid - off];
        __syncthreads();
        if (tid >= off) t[tid] += u;
        __syncthreads();
    }
    int run = t[tid] - local;
#pragma unroll
    for (int j = 0; j < 7; ++j) {
        int w = tid * 7 + j;
        if (w < BIN_NWG) { hist_all[w * PADC + b] = run; run += v[j]; }
    }
    if (tid == 255) chunk_cnt[b] = t[255];
}

__global__ void scan_chunks(const int* __restrict__ chunk_cnt, int* __restrict__ csum) {
    __shared__ int t[256];
    const int tid = threadIdx.x;
    int v = (tid < NCHUNKS) ? chunk_cnt[tid] : 0;
    t[tid] = v;
    __syncthreads();
    for (int off = 1; off < 256; off <<= 1) {
        int u = 0;
        if (tid >= off) u = t[tid - off];
        __syncthreads();
        if (tid >= off) t[tid] += u;
        __syncthreads();
    }
    if (tid < NCHUNKS) csum[tid] = t[tid] - v;
}

__global__ __launch_bounds__(256) void bin_edges(const int* __restrict__ erow,
                                                 const int* __restrict__ ecol,
                                                 const float* __restrict__ eval,
                                                 const int* __restrict__ hist_all,
                                                 const int* __restrict__ csum,
                                                 uint2* __restrict__ bin) {
    __shared__ int hist[256];
    __shared__ int scnt[256];
    __shared__ int delta[256];
    __shared__ uint2 rec[BIN_TILE];
    const int tid = threadIdx.x;
    const int base = blockIdx.x * BIN_TILE;

    hist[tid] = 0;
    __syncthreads();

    int r[8]; unsigned pk[8];
#pragma unroll
    for (int j = 0; j < 8; ++j) {
        int e = base + j * 256 + tid;
        if (e < N_EDGES) {
            r[j] = erow[e];
            pk[j] = (((unsigned)ecol[e]) << 15) | (f2bf(eval[e]) & 0x7FFFu);
            atomicAdd(&hist[r[j] >> CHUNK_SHIFT], 1);
        } else {
            r[j] = -1;
        }
    }
    __syncthreads();

    const int cntb = hist[tid];
    for (int off = 1; off < 256; off <<= 1) {
        int u = 0;
        if (tid >= off) u = hist[tid - off];
        __syncthreads();
        if (tid >= off) hist[tid] += u;
        __syncthreads();
    }
    const int excl = hist[tid] - cntb;
    if (tid < NCHUNKS)
        delta[tid] = csum[tid] + hist_all[blockIdx.x * PADC + tid] - excl;
    scnt[tid] = 0;
    __syncthreads();

#pragma unroll
    for (int j = 0; j < 8; ++j) {
        if (r[j] >= 0) {
            int b = r[j] >> CHUNK_SHIFT;
            int s = (b ? hist[b - 1] : 0) + atomicAdd(&scnt[b], 1);
            rec[s] = make_uint2(pk[j], (unsigned)r[j]);
        }
    }
    __syncthreads();

    const int n = min(BIN_TILE, N_EDGES - base);
    for (int s = tid; s < n; s += 256) {
        uint2 q = rec[s];
        bin[delta[(int)q.y >> CHUNK_SHIFT] + s] = q;
    }
}

__global__ __launch_bounds__(512) void sort_chunk(const int* __restrict__ csum,
                                                  const uint2* __restrict__ bin,
                                                  int* __restrict__ row_ptr,
                                                  unsigned* __restrict__ cv) {
    __shared__ int h[CHUNK];
    const int b = blockIdx.x;
    const int tid = threadIdx.x;
    const int start = csum[b];
    const int end = (b + 1 < NCHUNKS) ? csum[b + 1] : N_EDGES;

    h[tid] = 0;
    __syncthreads();
    {
        int i = start + tid;
        for (; i + 3 * 512 < end; i += 4 * 512) {
            int r0 = (int)bin[i].y, r1 = (int)bin[i + 512].y;
            int r2 = (int)bin[i + 1024].y, r3 = (int)bin[i + 1536].y;
            atomicAdd(&h[r0 & (CHUNK - 1)], 1);
            atomicAdd(&h[r1 & (CHUNK - 1)], 1);
            atomicAdd(&h[r2 & (CHUNK - 1)], 1);
            atomicAdd(&h[r3 & (CHUNK - 1)], 1);
        }
        for (; i < end; i += 512)
            atomicAdd(&h[(int)bin[i].y & (CHUNK - 1)], 1);
    }
    __syncthreads();

    const int cnt = h[tid];
    for (int off = 1; off < 512; off <<= 1) {
        int u = 0;
        if (tid >= off) u = h[tid - off];
        __syncthreads();
        if (tid >= off) h[tid] += u;
        __syncthreads();
    }
    const int rp = start + h[tid] - cnt;
    const int row = (b << CHUNK_SHIFT) + tid;
    if (row < N_NODES) row_ptr[row] = rp;
    if (b == NCHUNKS - 1 && tid == 0) row_ptr[N_NODES] = N_EDGES;
    __syncthreads();
    h[tid] = rp;
    __syncthreads();

    int i = start + tid;
    for (; i + 3 * 512 < end; i += 4 * 512) {
        uint2 q0 = bin[i], q1 = bin[i + 512], q2 = bin[i + 1024], q3 = bin[i + 1536];
        int p0 = atomicAdd(&h[(int)q0.y & (CHUNK - 1)], 1);
        int p1 = atomicAdd(&h[(int)q1.y & (CHUNK - 1)], 1);
        int p2 = atomicAdd(&h[(int)q2.y & (CHUNK - 1)], 1);
        int p3 = atomicAdd(&h[(int)q3.y & (CHUNK - 1)], 1);
        cv[p0] = q0.x; cv[p1] = q1.x; cv[p2] = q2.x; cv[p3] = q3.x;
    }
    for (; i < end; i += 512) {
        uint2 q = bin[i];
        int p = atomicAdd(&h[(int)q.y & (CHUNK - 1)], 1);
        cv[p] = q.x;
    }
}

// ---------------------------------------------------------------------------
// XCD-sliced gather. Each XCD (blockIdx%8 round-robin heuristic; correctness
// never depends on it) handles 2 feature-slices sequentially over all rows:
// gathers hit a 3.2 MB L2-RESIDENT slice instead of random reads over 51.2 MB
// (round-6 counters: 750 MB L2-miss traffic at 3.6 TB/s = the 210 us wall).
// Wave = 16 groups x 4 lanes: 16 edges in flight, 32 B gather per edge;
// 4-step shfl_xor group reduce; 32 B store per row (rows contiguous per wave
// -> full-line write combining). Output ts is slice-major like xs.
// ---------------------------------------------------------------------------
__global__ __launch_bounds__(256) void gather_sliced(const int* __restrict__ row_ptr,
                                                     const unsigned* __restrict__ cv,
                                                     const unsigned short* __restrict__ xs,
                                                     unsigned short* __restrict__ ts) {
    const int lane = threadIdx.x & 63;
    const int wv = threadIdx.x >> 6;
    const int xcd = blockIdx.x & 7;
    const int rank = (blockIdx.x >> 3) * 4 + wv;            // 0..1023 within xcd
    const int nw = (GAT_BLOCKS >> 3) * 4;                   // 1024 waves per xcd
    const int rows_per = (N_NODES + nw - 1) / nw;           // 98
    const int r0 = rank * rows_per;
    const int r1 = min(r0 + rows_per, N_NODES);
    const int g = lane >> 2, sub = lane & 3;

    for (int ph = 0; ph < 2; ++ph) {
        const int s = xcd * 2 + ph;
        const unsigned short* __restrict__ xsl = xs + (size_t)s * N_NODES * FS;
        unsigned short* __restrict__ tsl = ts + (size_t)s * N_NODES * FS;
        for (int row = r0; row < r1; ++row) {
            const int start = row_ptr[row];
            const int deg = row_ptr[row + 1] - start;
            const unsigned* __restrict__ p = cv + start;
            float a0 = 0.f, a1 = 0.f, a2 = 0.f, a3 = 0.f;
            for (int i = g; i < deg; i += 16) {
                unsigned e = p[i];
                float val = __uint_as_float((e & 0x7FFFu) << 16);
                uint2 gx = *(const uint2*)(xsl + (size_t)(e >> 15) * FS + sub * 4);
                a0 = fmaf(val, __uint_as_float(gx.x << 16), a0);
                a1 = fmaf(val, __uint_as_float(gx.x & 0xFFFF0000u), a1);
                a2 = fmaf(val, __uint_as_float(gx.y << 16), a2);
                a3 = fmaf(val, __uint_as_float(gx.y & 0xFFFF0000u), a3);
            }
#pragma unroll
            for (int m = 4; m <= 32; m <<= 1) {
                a0 += __shfl_xor(a0, m, 64);
                a1 += __shfl_xor(a1, m, 64);
                a2 += __shfl_xor(a2, m, 64);
                a3 += __shfl_xor(a3, m, 64);
            }
            if (lane < 4) {
                ushort4 o = make_ushort4(f2bf(a0), f2bf(a1), f2bf(a2), f2bf(a3));
                *(ushort4*)(tsl + (size_t)row * FS + lane * 4) = o;
            }
        }
    }
}

// ---------------------------------------------------------------------------
// out = relu(tmp @ W + bias) via bf16 MFMA 16x16x32. 64x256 block.
// A is SLICE-MAJOR tmp: k-slab [k0,k0+64) = slices k0/16..+3; thread
// (q=tid>>6, ar=tid&63) stages 32 B from slice k0/16+q, row gm (64 lanes
// consecutive -> 2 KB contiguous per wave instruction).
// ---------------------------------------------------------------------------
#define GBM 64
#define GBK 64
#define LDK 72

__global__ __launch_bounds__(256) void gemm_mfma(
    const unsigned short* __restrict__ A,    // slice-major tmp [16][N][16]
    const unsigned short* __restrict__ Bt,   // Wt bf16 [N][K] = [256][256]
    const float* __restrict__ bias,
    float* __restrict__ C, int M)
{
    __shared__ unsigned short As[GBM * LDK];
    __shared__ unsigned short Bs[UNITS * LDK];

    const int tid = threadIdx.x;
    const int lane = tid & 63;
    const int wave_n = tid >> 6;
    const int block_m = blockIdx.x * GBM;

    const int quad = lane >> 4;
    const int l16 = lane & 15;

    const int q = tid >> 6;                 // A staging: slice-within-slab
    const int ar = tid & 63;                // A staging: row

    f32x4 acc[4][4];
#pragma unroll
    for (int i = 0; i < 4; ++i)
#pragma unroll
        for (int j = 0; j < 4; ++j)
            acc[i][j] = {0.f, 0.f, 0.f, 0.f};

    for (int k0 = 0; k0 < DFEAT; k0 += GBK) {
        // --- stage A tile 64x64 from slice-major tmp (guarded) ---
        {
            const int gm = block_m + ar;
            const int s = (k0 >> 4) + q;
            uint4 v0 = {}, v1 = {};
            if (gm < M) {
                const uint4* src = (const uint4*)(A + ((size_t)s * N_NODES + gm) * FS);
                v0 = src[0]; v1 = src[1];
            }
            uint4* dst = (uint4*)&As[ar * LDK + q * 16];
            dst[0] = v0; dst[1] = v1;
        }
        // --- stage B tile 256x64: full 64-short row-slab (8x uint4) ---
        {
            const uint4* src = (const uint4*)(Bt + (size_t)tid * DFEAT + k0);
            uint4* dst = (uint4*)&Bs[tid * LDK];
            uint4 v0 = src[0], v1 = src[1], v2 = src[2], v3 = src[3];
            uint4 v4 = src[4], v5 = src[5], v6 = src[6], v7 = src[7];
            dst[0] = v0; dst[1] = v1; dst[2] = v2; dst[3] = v3;
            dst[4] = v4; dst[5] = v5; dst[6] = v6; dst[7] = v7;
        }
        __syncthreads();

#pragma unroll
        for (int kc = 0; kc < 2; ++kc) {
            const int ko = kc * 32 + quad * 8;
            bf16x8 af[4], bfr[4];
#pragma unroll
            for (int i = 0; i < 4; ++i)
                af[i] = *(const bf16x8*)&As[(i * 16 + l16) * LDK + ko];
#pragma unroll
            for (int j = 0; j < 4; ++j)
                bfr[j] = *(const bf16x8*)&Bs[(wave_n * 64 + j * 16 + l16) * LDK + ko];
#pragma unroll
            for (int i = 0; i < 4; ++i)
#pragma unroll
                for (int j = 0; j < 4; ++j)
                    acc[i][j] = __builtin_amdgcn_mfma_f32_16x16x32_bf16(
                        af[i], bfr[j], acc[i][j], 0, 0, 0);
        }
        __syncthreads();
    }

    // epilogue: bias + relu
#pragma unroll
    for (int j = 0; j < 4; ++j) {
        const int n = wave_n * 64 + j * 16 + l16;
        const float bj = bias[n];
#pragma unroll
        for (int i = 0; i < 4; ++i) {
            const int m0 = block_m + i * 16 + quad * 4;
#pragma unroll
            for (int rg = 0; rg < 4; ++rg) {
                const int m = m0 + rg;
                if (m < M)
                    C[(size_t)m * UNITS + n] = fmaxf(acc[i][j][rg] + bj, 0.f);
            }
        }
    }
}

extern "C" void kernel_launch(void* const* d_in, const int* in_sizes, int n_in,
                              void* d_out, int out_size, void* d_ws, size_t ws_size,
                              hipStream_t stream) {
    const int*   erow = (const int*)d_in[0];
    const int*   ecol = (const int*)d_in[1];
    const float* eval = (const float*)d_in[2];
    const float* x    = (const float*)d_in[3];
    const float* w    = (const float*)d_in[4];
    const float* bias = (const float*)d_in[5];
    float* out = (float*)d_out;

    // Workspace carve-up (bytes):
    //   tmp bf16 (slice-major) : 51,200,000
    //   row_ptr                : 400,016   (N_NODES+1 ints)
    //   csum                   : 1,024
    //   chunk_cnt              : 1,024
    //   cv (u32)               : 12,800,000
    //   Wt bf16                : 131,072
    //   bin (u64)              : 25,600,000
    //   hist_all               : 1563 x 208 x 4 = 1,300,416   total ~91.4 MB
    char* ws = (char*)d_ws;
    unsigned short* tmp       = (unsigned short*)(ws);
    int*            row_ptr   = (int*)(ws + 51200000);
    int*            csum      = (int*)(ws + 51600016);
    int*            chunk_cnt = (int*)(ws + 51601040);
    unsigned*       cv        = (unsigned*)(ws + 51602064);
    unsigned short* wt        = (unsigned short*)(ws + 64402064);
    uint2*          bin       = (uint2*)(ws + 64533136);
    int*            hist_all  = (int*)(ws + 90133136);

    // xs (slice-major bf16 x, 51.2 MB) lives in d_out — dead before gemm writes.
    unsigned short* xs = (unsigned short*)d_out;

    convert_xw<<<1563 + UNITS, 256, 0, stream>>>(x, xs, w, wt);

    // CSR build — round-3 measured-best structure
    chunk_hist<<<BIN_NWG, 256, 0, stream>>>(erow, hist_all);
    col_scan<<<NCHUNKS, 256, 0, stream>>>(hist_all, chunk_cnt);
    scan_chunks<<<1, 256, 0, stream>>>(chunk_cnt, csum);
    bin_edges<<<BIN_NWG, 256, 0, stream>>>(erow, ecol, eval, hist_all, csum, bin);
    sort_chunk<<<NCHUNKS, 512, 0, stream>>>(csum, bin, row_ptr, cv);

    // tmp = A_coo @ X, XCD-sliced (L2-resident per-XCD feature slices)
    gather_sliced<<<GAT_BLOCKS, 256, 0, stream>>>(row_ptr, cv, xs, tmp);

    // out = relu(tmp @ W + bias) via bf16 MFMA
    gemm_mfma<<<(N_NODES + GBM - 1) / GBM, 256, 0, stream>>>(tmp, wt, bias, out, N_NODES);
}

// Round 8
// 555.406 us; speedup vs baseline: 1.4169x; 1.4169x over previous
//
#include <hip/hip_runtime.h>
#include <hip/hip_bf16.h>

#define N_NODES 100000
#define N_EDGES 3200000
#define DFEAT 256
#define UNITS 256

#define CHUNK 512
#define CHUNK_SHIFT 9
#define NCHUNKS ((N_NODES + CHUNK - 1) / CHUNK)   // 196

#define BIN_TILE 2048
#define BIN_NWG ((N_EDGES + BIN_TILE - 1) / BIN_TILE)   // 1563
#define PADC 208                                  // padded chunk stride in hist_all

typedef short bf16x8 __attribute__((ext_vector_type(8)));
typedef float f32x4 __attribute__((ext_vector_type(4)));

// RNE float -> bf16 bits
__device__ __forceinline__ unsigned short f2bf(float f) {
    union { float f; unsigned u; } v; v.f = f;
    unsigned u = v.u;
    u += 0x7FFFu + ((u >> 16) & 1u);
    return (unsigned short)(u >> 16);
}

// ---------------------------------------------------------------------------
// Merged converts. Blocks [0,25000): x fp32 -> xh bf16 row-major (1 float4/thr).
// Blocks [25000,25256): W [k][n] fp32 -> Wt [n][k] bf16.
// ---------------------------------------------------------------------------
__global__ __launch_bounds__(256) void convert_xw(const float4* __restrict__ x4,
                                                  unsigned short* __restrict__ xh,
                                                  const float* __restrict__ w,
                                                  unsigned short* __restrict__ wt) {
    if (blockIdx.x < 25000) {
        size_t i = (size_t)blockIdx.x * 256 + threadIdx.x;   // 6.4M float4s
        float4 v = x4[i];
        ushort4 o = make_ushort4(f2bf(v.x), f2bf(v.y), f2bf(v.z), f2bf(v.w));
        *(ushort4*)&xh[i * 4] = o;
    } else {
        int n = blockIdx.x - 25000, k = threadIdx.x;
        wt[n * DFEAT + k] = f2bf(w[k * UNITS + n]);
    }
}

// ---------------------------------------------------------------------------
// CSR build — round-3 measured-best structure, verbatim.
// ---------------------------------------------------------------------------
__global__ __launch_bounds__(256) void chunk_hist(const int* __restrict__ erow,
                                                  int* __restrict__ hist_all) {
    __shared__ int h[256];
    const int tid = threadIdx.x;
    h[tid] = 0;
    __syncthreads();
    const int base = blockIdx.x * BIN_TILE;
#pragma unroll
    for (int j = 0; j < 8; ++j) {
        int e = base + j * 256 + tid;
        if (e < N_EDGES) atomicAdd(&h[erow[e] >> CHUNK_SHIFT], 1);
    }
    __syncthreads();
    if (tid < NCHUNKS) hist_all[blockIdx.x * PADC + tid] = h[tid];
}

__global__ __launch_bounds__(256) void col_scan(int* __restrict__ hist_all,
                                                int* __restrict__ chunk_cnt) {
    __shared__ int t[256];
    const int b = blockIdx.x;
    const int tid = threadIdx.x;
    int v[7]; int local = 0;
#pragma unroll
    for (int j = 0; j < 7; ++j) {
        int w = tid * 7 + j;
        v[j] = (w < BIN_NWG) ? hist_all[w * PADC + b] : 0;
        local += v[j];
    }
    t[tid] = local;
    __syncthreads();
    for (int off = 1; off < 256; off <<= 1) {
        int u = 0;
        if (tid >= off) u = t[tid - off];
        __syncthreads();
        if (tid >= off) t[tid] += u;
        __syncthreads();
    }
    int run = t[tid] - local;
#pragma unroll
    for (int j = 0; j < 7; ++j) {
        int w = tid * 7 + j;
        if (w < BIN_NWG) { hist_all[w * PADC + b] = run; run += v[j]; }
    }
    if (tid == 255) chunk_cnt[b] = t[255];
}

__global__ void scan_chunks(const int* __restrict__ chunk_cnt, int* __restrict__ csum) {
    __shared__ int t[256];
    const int tid = threadIdx.x;
    int v = (tid < NCHUNKS) ? chunk_cnt[tid] : 0;
    t[tid] = v;
    __syncthreads();
    for (int off = 1; off < 256; off <<= 1) {
        int u = 0;
        if (tid >= off) u = t[tid - off];
        __syncthreads();
        if (tid >= off) t[tid] += u;
        __syncthreads();
    }
    if (tid < NCHUNKS) csum[tid] = t[tid] - v;
}

__global__ __launch_bounds__(256) void bin_edges(const int* __restrict__ erow,
                                                 const int* __restrict__ ecol,
                                                 const float* __restrict__ eval,
                                                 const int* __restrict__ hist_all,
                                                 const int* __restrict__ csum,
                                                 uint2* __restrict__ bin) {
    __shared__ int hist[256];
    __shared__ int scnt[256];
    __shared__ int delta[256];
    __shared__ uint2 rec[BIN_TILE];
    const int tid = threadIdx.x;
    const int base = blockIdx.x * BIN_TILE;

    hist[tid] = 0;
    __syncthreads();

    int r[8]; unsigned pk[8];
#pragma unroll
    for (int j = 0; j < 8; ++j) {
        int e = base + j * 256 + tid;
        if (e < N_EDGES) {
            r[j] = erow[e];
            pk[j] = (((unsigned)ecol[e]) << 15) | (f2bf(eval[e]) & 0x7FFFu);
            atomicAdd(&hist[r[j] >> CHUNK_SHIFT], 1);
        } else {
            r[j] = -1;
        }
    }
    __syncthreads();

    const int cntb = hist[tid];
    for (int off = 1; off < 256; off <<= 1) {
        int u = 0;
        if (tid >= off) u = hist[tid - off];
        __syncthreads();
        if (tid >= off) hist[tid] += u;
        __syncthreads();
    }
    const int excl = hist[tid] - cntb;
    if (tid < NCHUNKS)
        delta[tid] = csum[tid] + hist_all[blockIdx.x * PADC + tid] - excl;
    scnt[tid] = 0;
    __syncthreads();

#pragma unroll
    for (int j = 0; j < 8; ++j) {
        if (r[j] >= 0) {
            int b = r[j] >> CHUNK_SHIFT;
            int s = (b ? hist[b - 1] : 0) + atomicAdd(&scnt[b], 1);
            rec[s] = make_uint2(pk[j], (unsigned)r[j]);
        }
    }
    __syncthreads();

    const int n = min(BIN_TILE, N_EDGES - base);
    for (int s = tid; s < n; s += 256) {
        uint2 q = rec[s];
        bin[delta[(int)q.y >> CHUNK_SHIFT] + s] = q;
    }
}

__global__ __launch_bounds__(512) void sort_chunk(const int* __restrict__ csum,
                                                  const uint2* __restrict__ bin,
                                                  int* __restrict__ row_ptr,
                                                  unsigned* __restrict__ cv) {
    __shared__ int h[CHUNK];
    const int b = blockIdx.x;
    const int tid = threadIdx.x;
    const int start = csum[b];
    const int end = (b + 1 < NCHUNKS) ? csum[b + 1] : N_EDGES;

    h[tid] = 0;
    __syncthreads();
    {
        int i = start + tid;
        for (; i + 3 * 512 < end; i += 4 * 512) {
            int r0 = (int)bin[i].y, r1 = (int)bin[i + 512].y;
            int r2 = (int)bin[i + 1024].y, r3 = (int)bin[i + 1536].y;
            atomicAdd(&h[r0 & (CHUNK - 1)], 1);
            atomicAdd(&h[r1 & (CHUNK - 1)], 1);
            atomicAdd(&h[r2 & (CHUNK - 1)], 1);
            atomicAdd(&h[r3 & (CHUNK - 1)], 1);
        }
        for (; i < end; i += 512)
            atomicAdd(&h[(int)bin[i].y & (CHUNK - 1)], 1);
    }
    __syncthreads();

    const int cnt = h[tid];
    for (int off = 1; off < 512; off <<= 1) {
        int u = 0;
        if (tid >= off) u = h[tid - off];
        __syncthreads();
        if (tid >= off) h[tid] += u;
        __syncthreads();
    }
    const int rp = start + h[tid] - cnt;
    const int row = (b << CHUNK_SHIFT) + tid;
    if (row < N_NODES) row_ptr[row] = rp;
    if (b == NCHUNKS - 1 && tid == 0) row_ptr[N_NODES] = N_EDGES;
    __syncthreads();
    h[tid] = rp;
    __syncthreads();

    int i = start + tid;
    for (; i + 3 * 512 < end; i += 4 * 512) {
        uint2 q0 = bin[i], q1 = bin[i + 512], q2 = bin[i + 1024], q3 = bin[i + 1536];
        int p0 = atomicAdd(&h[(int)q0.y & (CHUNK - 1)], 1);
        int p1 = atomicAdd(&h[(int)q1.y & (CHUNK - 1)], 1);
        int p2 = atomicAdd(&h[(int)q2.y & (CHUNK - 1)], 1);
        int p3 = atomicAdd(&h[(int)q3.y & (CHUNK - 1)], 1);
        cv[p0] = q0.x; cv[p1] = q1.x; cv[p2] = q2.x; cv[p3] = q3.x;
    }
    for (; i < end; i += 512) {
        uint2 q = bin[i];
        int p = atomicAdd(&h[(int)q.y & (CHUNK - 1)], 1);
        cv[p] = q.x;
    }
}

// ---------------------------------------------------------------------------
// Aggregate — round-3 verbatim (210 us, treated as this algorithm's floor).
// ---------------------------------------------------------------------------
__global__ __launch_bounds__(256) void gather_rows(const int* __restrict__ row_ptr,
                                                   const unsigned* __restrict__ cv,
                                                   const unsigned short* __restrict__ xh,
                                                   unsigned short* __restrict__ tmp) {
    const int row = blockIdx.x * 4 + (threadIdx.x >> 6);
    if (row >= N_NODES) return;
    const int lane = threadIdx.x & 63;
    const int start = row_ptr[row];
    const int deg = row_ptr[row + 1] - start;
    const unsigned* __restrict__ p = cv + start;
    const uint2* __restrict__ x2 = (const uint2*)xh;

    float a0 = 0.f, a1 = 0.f, a2 = 0.f, a3 = 0.f;
    int i = 0;
    for (; i + 7 < deg; i += 8) {
        unsigned e[8]; uint2 g[8];
#pragma unroll
        for (int j = 0; j < 8; ++j) e[j] = p[i + j];
#pragma unroll
        for (int j = 0; j < 8; ++j) g[j] = x2[(size_t)(e[j] >> 15) * 64 + lane];
#pragma unroll
        for (int j = 0; j < 8; ++j) {
            float v = __uint_as_float((e[j] & 0x7FFFu) << 16);
            a0 = fmaf(v, __uint_as_float(g[j].x << 16), a0);
            a1 = fmaf(v, __uint_as_float(g[j].x & 0xFFFF0000u), a1);
            a2 = fmaf(v, __uint_as_float(g[j].y << 16), a2);
            a3 = fmaf(v, __uint_as_float(g[j].y & 0xFFFF0000u), a3);
        }
    }
    for (; i + 3 < deg; i += 4) {
        unsigned e[4]; uint2 g[4];
#pragma unroll
        for (int j = 0; j < 4; ++j) e[j] = p[i + j];
#pragma unroll
        for (int j = 0; j < 4; ++j) g[j] = x2[(size_t)(e[j] >> 15) * 64 + lane];
#pragma unroll
        for (int j = 0; j < 4; ++j) {
            float v = __uint_as_float((e[j] & 0x7FFFu) << 16);
            a0 = fmaf(v, __uint_as_float(g[j].x << 16), a0);
            a1 = fmaf(v, __uint_as_float(g[j].x & 0xFFFF0000u), a1);
            a2 = fmaf(v, __uint_as_float(g[j].y << 16), a2);
            a3 = fmaf(v, __uint_as_float(g[j].y & 0xFFFF0000u), a3);
        }
    }
    for (; i < deg; ++i) {
        unsigned e0 = p[i];
        uint2 g0 = x2[(size_t)(e0 >> 15) * 64 + lane];
        float v0 = __uint_as_float((e0 & 0x7FFFu) << 16);
        a0 = fmaf(v0, __uint_as_float(g0.x << 16), a0);
        a1 = fmaf(v0, __uint_as_float(g0.x & 0xFFFF0000u), a1);
        a2 = fmaf(v0, __uint_as_float(g0.y << 16), a2);
        a3 = fmaf(v0, __uint_as_float(g0.y & 0xFFFF0000u), a3);
    }
    ushort4 o = make_ushort4(f2bf(a0), f2bf(a1), f2bf(a2), f2bf(a3));
    *(ushort4*)&tmp[(size_t)row * 256 + lane * 4] = o;
}

// ---------------------------------------------------------------------------
// out = relu(tmp @ W + bias) via bf16 MFMA 16x16x32. 64x256 block, 4 waves.
// NEW: A staged ONCE (full 64x256, 33.8 KB LDS, ~4 blocks/CU), ONE barrier
// per block; B fragments read directly from global (B = 128 KB, L2-hot for
// all 1563 blocks) — removes 7 barriers/block + all B LDS round-trips.
// ---------------------------------------------------------------------------
#define GBM 64
#define LDK2 264   // 256 + 8 shorts pad

__global__ __launch_bounds__(256) void gemm_mfma(
    const unsigned short* __restrict__ A,    // tmp bf16 [M][256]
    const unsigned short* __restrict__ Bt,   // Wt bf16 [N][K] = [256][256]
    const float* __restrict__ bias,
    float* __restrict__ C, int M)
{
    __shared__ unsigned short As[GBM * LDK2];   // 33792 B

    const int tid = threadIdx.x;
    const int lane = tid & 63;
    const int wave_n = tid >> 6;
    const int block_m = blockIdx.x * GBM;

    const int quad = lane >> 4;
    const int l16 = lane & 15;

    // --- stage A once: full 64x256 tile; thread t: row t>>2, 128B segment t&3
    {
        const int ar = tid >> 2;
        const int seg = tid & 3;
        const int gm = block_m + ar;
        uint4 v[8] = {};
        if (gm < M) {
            const uint4* src = (const uint4*)(A + (size_t)gm * DFEAT + seg * 64);
#pragma unroll
            for (int j = 0; j < 8; ++j) v[j] = src[j];
        }
        uint4* dst = (uint4*)&As[ar * LDK2 + seg * 64];
#pragma unroll
        for (int j = 0; j < 8; ++j) dst[j] = v[j];
    }
    __syncthreads();

    f32x4 acc[4][4];
#pragma unroll
    for (int i = 0; i < 4; ++i)
#pragma unroll
        for (int j = 0; j < 4; ++j)
            acc[i][j] = {0.f, 0.f, 0.f, 0.f};

#pragma unroll
    for (int ks = 0; ks < 8; ++ks) {
        const int ko = ks * 32 + quad * 8;
        bf16x8 af[4], bfr[4];
#pragma unroll
        for (int i = 0; i < 4; ++i)
            af[i] = *(const bf16x8*)&As[(i * 16 + l16) * LDK2 + ko];
#pragma unroll
        for (int j = 0; j < 4; ++j)
            bfr[j] = *(const bf16x8*)&Bt[(size_t)(wave_n * 64 + j * 16 + l16) * DFEAT + ko];
#pragma unroll
        for (int i = 0; i < 4; ++i)
#pragma unroll
            for (int j = 0; j < 4; ++j)
                acc[i][j] = __builtin_amdgcn_mfma_f32_16x16x32_bf16(
                    af[i], bfr[j], acc[i][j], 0, 0, 0);
    }

    // epilogue: bias + relu
#pragma unroll
    for (int j = 0; j < 4; ++j) {
        const int n = wave_n * 64 + j * 16 + l16;
        const float bj = bias[n];
#pragma unroll
        for (int i = 0; i < 4; ++i) {
            const int m0 = block_m + i * 16 + quad * 4;
#pragma unroll
            for (int rg = 0; rg < 4; ++rg) {
                const int m = m0 + rg;
                if (m < M)
                    C[(size_t)m * UNITS + n] = fmaxf(acc[i][j][rg] + bj, 0.f);
            }
        }
    }
}

extern "C" void kernel_launch(void* const* d_in, const int* in_sizes, int n_in,
                              void* d_out, int out_size, void* d_ws, size_t ws_size,
                              hipStream_t stream) {
    const int*   erow = (const int*)d_in[0];
    const int*   ecol = (const int*)d_in[1];
    const float* eval = (const float*)d_in[2];
    const float* x    = (const float*)d_in[3];
    const float* w    = (const float*)d_in[4];
    const float* bias = (const float*)d_in[5];
    float* out = (float*)d_out;

    // Workspace carve-up (round-3 layout):
    //   tmp bf16   : 51,200,000
    //   row_ptr    : 400,016   (N_NODES+1 ints)
    //   csum       : 1,024
    //   chunk_cnt  : 1,024
    //   cv (u32)   : 12,800,000
    //   Wt bf16    : 131,072
    //   bin (u64)  : 25,600,000
    //   hist_all   : 1563 x 208 x 4 = 1,300,416   total ~91.4 MB
    char* ws = (char*)d_ws;
    unsigned short* tmp       = (unsigned short*)(ws);
    int*            row_ptr   = (int*)(ws + 51200000);
    int*            csum      = (int*)(ws + 51600016);
    int*            chunk_cnt = (int*)(ws + 51601040);
    unsigned*       cv        = (unsigned*)(ws + 51602064);
    unsigned short* wt        = (unsigned short*)(ws + 64402064);
    uint2*          bin       = (uint2*)(ws + 64533136);
    int*            hist_all  = (int*)(ws + 90133136);

    // xh (bf16 x, 51.2 MB) lives in d_out — dead before gemm writes out.
    unsigned short* xh = (unsigned short*)d_out;

    convert_xw<<<25000 + UNITS, 256, 0, stream>>>((const float4*)x, xh, w, wt);

    // CSR build — round-3 measured-best structure
    chunk_hist<<<BIN_NWG, 256, 0, stream>>>(erow, hist_all);
    col_scan<<<NCHUNKS, 256, 0, stream>>>(hist_all, chunk_cnt);
    scan_chunks<<<1, 256, 0, stream>>>(chunk_cnt, csum);
    bin_edges<<<BIN_NWG, 256, 0, stream>>>(erow, ecol, eval, hist_all, csum, bin);
    sort_chunk<<<NCHUNKS, 512, 0, stream>>>(csum, bin, row_ptr, cv);

    // tmp = A_coo @ X
    gather_rows<<<(N_NODES + 3) / 4, 256, 0, stream>>>(row_ptr, cv, xh, tmp);

    // out = relu(tmp @ W + bias)
    gemm_mfma<<<(N_NODES + GBM - 1) / GBM, 256, 0, stream>>>(tmp, wt, bias, out, N_NODES);
}

// Round 9
// 511.872 us; speedup vs baseline: 1.5374x; 1.0850x over previous
//
#include <hip/hip_runtime.h>
#include <hip/hip_bf16.h>

#define N_NODES 100000
#define N_EDGES 3200000
#define DFEAT 256
#define UNITS 256

#define CHUNK 512
#define CHUNK_SHIFT 9
#define NCHUNKS ((N_NODES + CHUNK - 1) / CHUNK)   // 196

#define BIN_TILE 2048
#define BIN_NWG ((N_EDGES + BIN_TILE - 1) / BIN_TILE)   // 1563
#define PADC 208                                  // padded chunk stride in hist_all

typedef short bf16x8 __attribute__((ext_vector_type(8)));
typedef float f32x4 __attribute__((ext_vector_type(4)));

// RNE float -> bf16 bits
__device__ __forceinline__ unsigned short f2bf(float f) {
    union { float f; unsigned u; } v; v.f = f;
    unsigned u = v.u;
    u += 0x7FFFu + ((u >> 16) & 1u);
    return (unsigned short)(u >> 16);
}

// ---------------------------------------------------------------------------
// Merged prelude: blocks [0,25000) convert x fp32->bf16 (1 float4/thr);
// [25000,25256) transpose-convert W; [25256,26819) = chunk_hist (round-3).
// All independent — one launch instead of two.
// ---------------------------------------------------------------------------
__global__ __launch_bounds__(256) void convert_hist(const float4* __restrict__ x4,
                                                    unsigned short* __restrict__ xh,
                                                    const float* __restrict__ w,
                                                    unsigned short* __restrict__ wt,
                                                    const int* __restrict__ erow,
                                                    int* __restrict__ hist_all) {
    if (blockIdx.x < 25000) {
        size_t i = (size_t)blockIdx.x * 256 + threadIdx.x;   // 6.4M float4s
        float4 v = x4[i];
        ushort4 o = make_ushort4(f2bf(v.x), f2bf(v.y), f2bf(v.z), f2bf(v.w));
        *(ushort4*)&xh[i * 4] = o;
    } else if (blockIdx.x < 25256) {
        int n = blockIdx.x - 25000, k = threadIdx.x;
        wt[n * DFEAT + k] = f2bf(w[k * UNITS + n]);
    } else {
        __shared__ int h[256];
        const int wg = blockIdx.x - 25256;
        const int tid = threadIdx.x;
        h[tid] = 0;
        __syncthreads();
        const int base = wg * BIN_TILE;
#pragma unroll
        for (int j = 0; j < 8; ++j) {
            int e = base + j * 256 + tid;
            if (e < N_EDGES) atomicAdd(&h[erow[e] >> CHUNK_SHIFT], 1);
        }
        __syncthreads();
        if (tid < NCHUNKS) hist_all[wg * PADC + tid] = h[tid];
    }
}

// ---------------------------------------------------------------------------
// CSR build — round-3 measured-best structure, verbatim.
// ---------------------------------------------------------------------------
__global__ __launch_bounds__(256) void col_scan(int* __restrict__ hist_all,
                                                int* __restrict__ chunk_cnt) {
    __shared__ int t[256];
    const int b = blockIdx.x;
    const int tid = threadIdx.x;
    int v[7]; int local = 0;
#pragma unroll
    for (int j = 0; j < 7; ++j) {
        int w = tid * 7 + j;
        v[j] = (w < BIN_NWG) ? hist_all[w * PADC + b] : 0;
        local += v[j];
    }
    t[tid] = local;
    __syncthreads();
    for (int off = 1; off < 256; off <<= 1) {
        int u = 0;
        if (tid >= off) u = t[tid - off];
        __syncthreads();
        if (tid >= off) t[tid] += u;
        __syncthreads();
    }
    int run = t[tid] - local;
#pragma unroll
    for (int j = 0; j < 7; ++j) {
        int w = tid * 7 + j;
        if (w < BIN_NWG) { hist_all[w * PADC + b] = run; run += v[j]; }
    }
    if (tid == 255) chunk_cnt[b] = t[255];
}

__global__ void scan_chunks(const int* __restrict__ chunk_cnt, int* __restrict__ csum) {
    __shared__ int t[256];
    const int tid = threadIdx.x;
    int v = (tid < NCHUNKS) ? chunk_cnt[tid] : 0;
    t[tid] = v;
    __syncthreads();
    for (int off = 1; off < 256; off <<= 1) {
        int u = 0;
        if (tid >= off) u = t[tid - off];
        __syncthreads();
        if (tid >= off) t[tid] += u;
        __syncthreads();
    }
    if (tid < NCHUNKS) csum[tid] = t[tid] - v;
}

__global__ __launch_bounds__(256) void bin_edges(const int* __restrict__ erow,
                                                 const int* __restrict__ ecol,
                                                 const float* __restrict__ eval,
                                                 const int* __restrict__ hist_all,
                                                 const int* __restrict__ csum,
                                                 uint2* __restrict__ bin) {
    __shared__ int hist[256];
    __shared__ int scnt[256];
    __shared__ int delta[256];
    __shared__ uint2 rec[BIN_TILE];
    const int tid = threadIdx.x;
    const int base = blockIdx.x * BIN_TILE;

    hist[tid] = 0;
    __syncthreads();

    int r[8]; unsigned pk[8];
#pragma unroll
    for (int j = 0; j < 8; ++j) {
        int e = base + j * 256 + tid;
        if (e < N_EDGES) {
            r[j] = erow[e];
            pk[j] = (((unsigned)ecol[e]) << 15) | (f2bf(eval[e]) & 0x7FFFu);
            atomicAdd(&hist[r[j] >> CHUNK_SHIFT], 1);
        } else {
            r[j] = -1;
        }
    }
    __syncthreads();

    const int cntb = hist[tid];
    for (int off = 1; off < 256; off <<= 1) {
        int u = 0;
        if (tid >= off) u = hist[tid - off];
        __syncthreads();
        if (tid >= off) hist[tid] += u;
        __syncthreads();
    }
    const int excl = hist[tid] - cntb;
    if (tid < NCHUNKS)
        delta[tid] = csum[tid] + hist_all[blockIdx.x * PADC + tid] - excl;
    scnt[tid] = 0;
    __syncthreads();

#pragma unroll
    for (int j = 0; j < 8; ++j) {
        if (r[j] >= 0) {
            int b = r[j] >> CHUNK_SHIFT;
            int s = (b ? hist[b - 1] : 0) + atomicAdd(&scnt[b], 1);
            rec[s] = make_uint2(pk[j], (unsigned)r[j]);
        }
    }
    __syncthreads();

    const int n = min(BIN_TILE, N_EDGES - base);
    for (int s = tid; s < n; s += 256) {
        uint2 q = rec[s];
        bin[delta[(int)q.y >> CHUNK_SHIFT] + s] = q;
    }
}

__global__ __launch_bounds__(512) void sort_chunk(const int* __restrict__ csum,
                                                  const uint2* __restrict__ bin,
                                                  int* __restrict__ row_ptr,
                                                  unsigned* __restrict__ cv) {
    __shared__ int h[CHUNK];
    const int b = blockIdx.x;
    const int tid = threadIdx.x;
    const int start = csum[b];
    const int end = (b + 1 < NCHUNKS) ? csum[b + 1] : N_EDGES;

    h[tid] = 0;
    __syncthreads();
    {
        int i = start + tid;
        for (; i + 3 * 512 < end; i += 4 * 512) {
            int r0 = (int)bin[i].y, r1 = (int)bin[i + 512].y;
            int r2 = (int)bin[i + 1024].y, r3 = (int)bin[i + 1536].y;
            atomicAdd(&h[r0 & (CHUNK - 1)], 1);
            atomicAdd(&h[r1 & (CHUNK - 1)], 1);
            atomicAdd(&h[r2 & (CHUNK - 1)], 1);
            atomicAdd(&h[r3 & (CHUNK - 1)], 1);
        }
        for (; i < end; i += 512)
            atomicAdd(&h[(int)bin[i].y & (CHUNK - 1)], 1);
    }
    __syncthreads();

    const int cnt = h[tid];
    for (int off = 1; off < 512; off <<= 1) {
        int u = 0;
        if (tid >= off) u = h[tid - off];
        __syncthreads();
        if (tid >= off) h[tid] += u;
        __syncthreads();
    }
    const int rp = start + h[tid] - cnt;
    const int row = (b << CHUNK_SHIFT) + tid;
    if (row < N_NODES) row_ptr[row] = rp;
    if (b == NCHUNKS - 1 && tid == 0) row_ptr[N_NODES] = N_EDGES;
    __syncthreads();
    h[tid] = rp;
    __syncthreads();

    int i = start + tid;
    for (; i + 3 * 512 < end; i += 4 * 512) {
        uint2 q0 = bin[i], q1 = bin[i + 512], q2 = bin[i + 1024], q3 = bin[i + 1536];
        int p0 = atomicAdd(&h[(int)q0.y & (CHUNK - 1)], 1);
        int p1 = atomicAdd(&h[(int)q1.y & (CHUNK - 1)], 1);
        int p2 = atomicAdd(&h[(int)q2.y & (CHUNK - 1)], 1);
        int p3 = atomicAdd(&h[(int)q3.y & (CHUNK - 1)], 1);
        cv[p0] = q0.x; cv[p1] = q1.x; cv[p2] = q2.x; cv[p3] = q3.x;
    }
    for (; i < end; i += 512) {
        uint2 q = bin[i];
        int p = atomicAdd(&h[(int)q.y & (CHUNK - 1)], 1);
        cv[p] = q.x;
    }
}

// ---------------------------------------------------------------------------
// FUSED gather + GEMM. Block = 512 thr (8 waves) owns 32 rows (N_NODES =
// 32 x 3125 exactly). Phase 1: each wave gathers 4 full rows (round-3 code,
// proven 211us form) into a 16.9 KB LDS tile (bf16). One barrier. Phase 2:
// MFMA 32x256: wave w computes cols w*32..+31 (2x2 fragments, acc=16 VGPR),
// B read direct from L2 (128 KB matrix, hot). Eliminates the tmp round trip
// (50 MB write + 51.2 MB read) and one launch.
// ---------------------------------------------------------------------------
#define FB 32
#define FLD 264   // LDS row stride in shorts (16B pad -> 2-way max on frag reads)

__global__ __launch_bounds__(512) void gather_gemm(
    const int* __restrict__ row_ptr,
    const unsigned* __restrict__ cv,
    const unsigned short* __restrict__ xh,
    const unsigned short* __restrict__ Bt,   // Wt bf16 [N][K] = [256][256]
    const float* __restrict__ bias,
    float* __restrict__ C)
{
    __shared__ unsigned short As[FB * FLD];   // 16896 B

    const int tid = threadIdx.x;
    const int lane = tid & 63;
    const int wv = tid >> 6;                  // 0..7
    const int block_m = blockIdx.x * FB;
    const uint2* __restrict__ x2 = (const uint2*)xh;

    // ---- phase 1: gather 4 rows per wave into As ----
#pragma unroll
    for (int rr = 0; rr < 4; ++rr) {
        const int rl = wv * 4 + rr;
        const int row = block_m + rl;
        const int start = row_ptr[row];
        const int deg = row_ptr[row + 1] - start;
        const unsigned* __restrict__ p = cv + start;

        float a0 = 0.f, a1 = 0.f, a2 = 0.f, a3 = 0.f;
        int i = 0;
        for (; i + 7 < deg; i += 8) {
            unsigned e[8]; uint2 g[8];
#pragma unroll
            for (int j = 0; j < 8; ++j) e[j] = p[i + j];
#pragma unroll
            for (int j = 0; j < 8; ++j) g[j] = x2[(size_t)(e[j] >> 15) * 64 + lane];
#pragma unroll
            for (int j = 0; j < 8; ++j) {
                float v = __uint_as_float((e[j] & 0x7FFFu) << 16);
                a0 = fmaf(v, __uint_as_float(g[j].x << 16), a0);
                a1 = fmaf(v, __uint_as_float(g[j].x & 0xFFFF0000u), a1);
                a2 = fmaf(v, __uint_as_float(g[j].y << 16), a2);
                a3 = fmaf(v, __uint_as_float(g[j].y & 0xFFFF0000u), a3);
            }
        }
        for (; i + 3 < deg; i += 4) {
            unsigned e[4]; uint2 g[4];
#pragma unroll
            for (int j = 0; j < 4; ++j) e[j] = p[i + j];
#pragma unroll
            for (int j = 0; j < 4; ++j) g[j] = x2[(size_t)(e[j] >> 15) * 64 + lane];
#pragma unroll
            for (int j = 0; j < 4; ++j) {
                float v = __uint_as_float((e[j] & 0x7FFFu) << 16);
                a0 = fmaf(v, __uint_as_float(g[j].x << 16), a0);
                a1 = fmaf(v, __uint_as_float(g[j].x & 0xFFFF0000u), a1);
                a2 = fmaf(v, __uint_as_float(g[j].y << 16), a2);
                a3 = fmaf(v, __uint_as_float(g[j].y & 0xFFFF0000u), a3);
            }
        }
        for (; i < deg; ++i) {
            unsigned e0 = p[i];
            uint2 g0 = x2[(size_t)(e0 >> 15) * 64 + lane];
            float v0 = __uint_as_float((e0 & 0x7FFFu) << 16);
            a0 = fmaf(v0, __uint_as_float(g0.x << 16), a0);
            a1 = fmaf(v0, __uint_as_float(g0.x & 0xFFFF0000u), a1);
            a2 = fmaf(v0, __uint_as_float(g0.y << 16), a2);
            a3 = fmaf(v0, __uint_as_float(g0.y & 0xFFFF0000u), a3);
        }
        ushort4 o = make_ushort4(f2bf(a0), f2bf(a1), f2bf(a2), f2bf(a3));
        *(ushort4*)&As[rl * FLD + lane * 4] = o;
    }
    __syncthreads();

    // ---- phase 2: MFMA 32x256 ----
    const int quad = lane >> 4;
    const int l16 = lane & 15;

    f32x4 acc[2][2];
#pragma unroll
    for (int i = 0; i < 2; ++i)
#pragma unroll
        for (int j = 0; j < 2; ++j)
            acc[i][j] = {0.f, 0.f, 0.f, 0.f};

#pragma unroll
    for (int ks = 0; ks < 8; ++ks) {
        const int ko = ks * 32 + quad * 8;
        bf16x8 af[2], bfr[2];
#pragma unroll
        for (int i = 0; i < 2; ++i)
            af[i] = *(const bf16x8*)&As[(i * 16 + l16) * FLD + ko];
#pragma unroll
        for (int j = 0; j < 2; ++j)
            bfr[j] = *(const bf16x8*)&Bt[(size_t)(wv * 32 + j * 16 + l16) * DFEAT + ko];
#pragma unroll
        for (int i = 0; i < 2; ++i)
#pragma unroll
            for (int j = 0; j < 2; ++j)
                acc[i][j] = __builtin_amdgcn_mfma_f32_16x16x32_bf16(
                    af[i], bfr[j], acc[i][j], 0, 0, 0);
    }

    // epilogue: bias + relu (N_NODES multiple of 32 -> no M guard)
#pragma unroll
    for (int j = 0; j < 2; ++j) {
        const int n = wv * 32 + j * 16 + l16;
        const float bj = bias[n];
#pragma unroll
        for (int i = 0; i < 2; ++i) {
            const int m0 = block_m + i * 16 + quad * 4;
#pragma unroll
            for (int rg = 0; rg < 4; ++rg) {
                const int m = m0 + rg;
                C[(size_t)m * UNITS + n] = fmaxf(acc[i][j][rg] + bj, 0.f);
            }
        }
    }
}

extern "C" void kernel_launch(void* const* d_in, const int* in_sizes, int n_in,
                              void* d_out, int out_size, void* d_ws, size_t ws_size,
                              hipStream_t stream) {
    const int*   erow = (const int*)d_in[0];
    const int*   ecol = (const int*)d_in[1];
    const float* eval = (const float*)d_in[2];
    const float* x    = (const float*)d_in[3];
    const float* w    = (const float*)d_in[4];
    const float* bias = (const float*)d_in[5];
    float* out = (float*)d_out;

    // Workspace carve-up (round-3 layout, tmp slot now holds xh — the fused
    // kernel writes d_out while gathers read xh, so xh can NOT live in d_out):
    //   xh bf16    : 51,200,000
    //   row_ptr    : 400,016   (N_NODES+1 ints)
    //   csum       : 1,024
    //   chunk_cnt  : 1,024
    //   cv (u32)   : 12,800,000
    //   Wt bf16    : 131,072
    //   bin (u64)  : 25,600,000
    //   hist_all   : 1563 x 208 x 4 = 1,300,416   total ~91.4 MB
    char* ws = (char*)d_ws;
    unsigned short* xh        = (unsigned short*)(ws);
    int*            row_ptr   = (int*)(ws + 51200000);
    int*            csum      = (int*)(ws + 51600016);
    int*            chunk_cnt = (int*)(ws + 51601040);
    unsigned*       cv        = (unsigned*)(ws + 51602064);
    unsigned short* wt        = (unsigned short*)(ws + 64402064);
    uint2*          bin       = (uint2*)(ws + 64533136);
    int*            hist_all  = (int*)(ws + 90133136);

    // converts + chunk_hist, one launch
    convert_hist<<<25000 + UNITS + BIN_NWG, 256, 0, stream>>>(
        (const float4*)x, xh, w, wt, erow, hist_all);

    // CSR build — round-3 measured-best structure
    col_scan<<<NCHUNKS, 256, 0, stream>>>(hist_all, chunk_cnt);
    scan_chunks<<<1, 256, 0, stream>>>(chunk_cnt, csum);
    bin_edges<<<BIN_NWG, 256, 0, stream>>>(erow, ecol, eval, hist_all, csum, bin);
    sort_chunk<<<NCHUNKS, 512, 0, stream>>>(csum, bin, row_ptr, cv);

    // fused: tmp-row gather (LDS) -> MFMA -> relu(+bias) -> out
    gather_gemm<<<N_NODES / FB, 512, 0, stream>>>(row_ptr, cv, xh, wt, bias, out);
}